// Round 1
// baseline (254.202 us; speedup 1.0000x reference)
//
#include <hip/hip_runtime.h>
#include <math.h>

#define NCLS 20
#define IGNORE_IDX 255
#define LOG2E 1.4426950408889634f

__device__ __forceinline__ float wave_reduce(float v) {
#pragma unroll
  for (int off = 32; off > 0; off >>= 1) v += __shfl_xor(v, off, 64);
  return v;
}

__device__ __forceinline__ float neg_log_clamped(float x, bool cond) {
  if (!cond) return 0.0f;
  float xs = fmaxf(x, 1e-38f);
  return fminf(-logf(xs), 100.0f);
}

// ws layout: [0..19] sum_p, [20..39] nominator, [40..59] ct_count
__global__ __launch_bounds__(256) void pass1(const float* __restrict__ pred,
                                             const int* __restrict__ target,
                                             float* __restrict__ ws, int N) {
  __shared__ float s_acc[3 * NCLS];
  const int tid = threadIdx.x;
  for (int i = tid; i < 3 * NCLS; i += blockDim.x) s_acc[i] = 0.0f;
  __syncthreads();

  float acc[NCLS];
#pragma unroll
  for (int c = 0; c < NCLS; ++c) acc[c] = 0.0f;

  const int nq = N >> 2;  // N divisible by 4 for this problem
  const int stride = gridDim.x * blockDim.x;
  for (int q = blockIdx.x * blockDim.x + tid; q < nq; q += stride) {
    const int n = q << 2;
    float4 x[NCLS];
#pragma unroll
    for (int c = 0; c < NCLS; ++c)
      x[c] = *reinterpret_cast<const float4*>(pred + (size_t)c * N + n);

    // per-voxel max over classes
    float4 m = x[0];
#pragma unroll
    for (int c = 1; c < NCLS; ++c) {
      m.x = fmaxf(m.x, x[c].x);
      m.y = fmaxf(m.y, x[c].y);
      m.z = fmaxf(m.z, x[c].z);
      m.w = fmaxf(m.w, x[c].w);
    }

    const int4 t4 = *reinterpret_cast<const int4*>(target + n);

    float4 s = make_float4(0.0f, 0.0f, 0.0f, 0.0f);
    float pt0 = 0.0f, pt1 = 0.0f, pt2 = 0.0f, pt3 = 0.0f;
#pragma unroll
    for (int c = 0; c < NCLS; ++c) {
      x[c].x = __builtin_amdgcn_exp2f((x[c].x - m.x) * LOG2E);
      x[c].y = __builtin_amdgcn_exp2f((x[c].y - m.y) * LOG2E);
      x[c].z = __builtin_amdgcn_exp2f((x[c].z - m.z) * LOG2E);
      x[c].w = __builtin_amdgcn_exp2f((x[c].w - m.w) * LOG2E);
      s.x += x[c].x; s.y += x[c].y; s.z += x[c].z; s.w += x[c].w;
      pt0 = (c == t4.x) ? x[c].x : pt0;
      pt1 = (c == t4.y) ? x[c].y : pt1;
      pt2 = (c == t4.z) ? x[c].z : pt2;
      pt3 = (c == t4.w) ? x[c].w : pt3;
    }

    const float r0 = __builtin_amdgcn_rcpf(s.x);
    const float r1 = __builtin_amdgcn_rcpf(s.y);
    const float r2 = __builtin_amdgcn_rcpf(s.z);
    const float r3 = __builtin_amdgcn_rcpf(s.w);

    const bool m0 = (t4.x != IGNORE_IDX);
    const bool m1 = (t4.y != IGNORE_IDX);
    const bool m2 = (t4.z != IGNORE_IDX);
    const bool m3 = (t4.w != IGNORE_IDX);
    const float w0 = m0 ? r0 : 0.0f;
    const float w1 = m1 ? r1 : 0.0f;
    const float w2 = m2 ? r2 : 0.0f;
    const float w3 = m3 ? r3 : 0.0f;

    // sum_p[c] += p_c over the 4 voxels (masked)
#pragma unroll
    for (int c = 0; c < NCLS; ++c)
      acc[c] += x[c].x * w0 + x[c].y * w1 + x[c].z * w2 + x[c].w * w3;

    // nominator / count via LDS atomics (guarded: t may be 255)
    if (m0) { atomicAdd(&s_acc[NCLS + t4.x], pt0 * w0); atomicAdd(&s_acc[2 * NCLS + t4.x], 1.0f); }
    if (m1) { atomicAdd(&s_acc[NCLS + t4.y], pt1 * w1); atomicAdd(&s_acc[2 * NCLS + t4.y], 1.0f); }
    if (m2) { atomicAdd(&s_acc[NCLS + t4.z], pt2 * w2); atomicAdd(&s_acc[2 * NCLS + t4.z], 1.0f); }
    if (m3) { atomicAdd(&s_acc[NCLS + t4.w], pt3 * w3); atomicAdd(&s_acc[2 * NCLS + t4.w], 1.0f); }
  }

  // block-reduce sum_p: wave butterfly, then lane0 -> LDS
#pragma unroll
  for (int c = 0; c < NCLS; ++c) {
    float v = wave_reduce(acc[c]);
    if ((tid & 63) == 0) atomicAdd(&s_acc[c], v);
  }
  __syncthreads();

  if (tid < 3 * NCLS) atomicAdd(&ws[tid], s_acc[tid]);
}

__global__ __launch_bounds__(64) void pass2(const float* __restrict__ ws,
                                            float* __restrict__ out) {
  const int lane = threadIdx.x;
  const float cnt = (lane < NCLS) ? ws[2 * NCLS + lane] : 0.0f;
  const float n_masked = wave_reduce(cnt);

  float loss = 0.0f, validf = 0.0f;
  if (lane < NCLS) {
    const float sump = ws[lane];
    const float nom = ws[NCLS + lane];
    const bool valid = cnt > 0.0f;
    const float prec = nom / fmaxf(sump, 1e-38f);
    const float rec = nom / fmaxf(cnt, 1.0f);
    const float negc = n_masked - cnt;
    const float specn = n_masked - sump - cnt + nom;
    const float spec = specn / fmaxf(negc, 1.0f);
    loss = neg_log_clamped(prec, valid && (sump > 0.0f)) +
           neg_log_clamped(rec, valid) +
           neg_log_clamped(spec, valid && (negc > 0.0f));
    validf = valid ? 1.0f : 0.0f;
  }
  loss = wave_reduce(loss);
  validf = wave_reduce(validf);
  if (lane == 0) out[0] = loss / validf;
}

extern "C" void kernel_launch(void* const* d_in, const int* in_sizes, int n_in,
                              void* d_out, int out_size, void* d_ws, size_t ws_size,
                              hipStream_t stream) {
  const float* pred = (const float*)d_in[0];
  const int* target = (const int*)d_in[1];
  const int N = in_sizes[1];  // voxel count; C = in_sizes[0]/N = 20
  float* ws = (float*)d_ws;

  hipMemsetAsync(d_ws, 0, 3 * NCLS * sizeof(float), stream);
  pass1<<<768, 256, 0, stream>>>(pred, target, ws, N);
  pass2<<<1, 64, 0, stream>>>(ws, (float*)d_out);
}